// Round 1
// 1395.852 us; speedup vs baseline: 1.0762x; 1.0762x over previous
//
#include <hip/hip_runtime.h>

// EIRNN: B=256,T=512,I=128,H=512,O=64; alpha=0.2, softplus beta=8, thresh=20.
// R2: single-hop tagged h-exchange. R1 spent ~3-4 IF$ round trips per step:
// sc1 store drain (s_waitcnt 0) -> flag store -> consumer flag-poll -> data
// fetch. R2 fuses tag+payload into one atomic u64 {hi: u32 tag = t+1,
// lo: 2 x f16 h-pair} so consumers poll the DATA words directly: the producer
// fire-and-forgets its stores (no drain, no flag), the consumer's freshness
// check and payload arrive in the same 8B transaction. Double buffer keeps it
// safe: buf[t&1] is only overwritten at t+2, and reaching t+2 requires the
// producer to have gathered h_{t+1}, which requires every consumer to have
// passed its B1(t) -- i.e. finished polling h_t. So a poll for tag t never
// races an overwrite.
// Also: own-shard columns short-circuit through LDS (hg double-buffered by
// step parity), which lets us drop the second barrier -- 1 barrier/step.
// Readout kept as R1 (K-split atomicAdd) to isolate the exchange change.

#define BB 256
#define TT 512
#define II 128
#define HH 512
#define OO 64
#define RG 16   // batch rows per row-group
#define JC 64   // h-columns per shard block
#define NG 16   // row-groups
#define NC 8    // shard blocks per group

typedef _Float16 f16;
typedef f16 f16x8 __attribute__((ext_vector_type(8)));
typedef float f32x4 __attribute__((ext_vector_type(4)));

__global__ __launch_bounds__(256, 1)
void eirnn_persist(const float* __restrict__ x,
                   const float* __restrict__ Wxh,
                   const float* __restrict__ Whh,
                   const float* __restrict__ bh,
                   const float* __restrict__ Wout,
                   const float* __restrict__ bout,
                   float* __restrict__ yout,
                   unsigned long long* __restrict__ hbuf) // 2 * (B*H/2) tagged u64
{
    const int tid  = threadIdx.x;
    const int bid  = blockIdx.x;
    const int wave = tid >> 6;
    const int lane = tid & 63;
    const int quad = lane >> 4;
    const int l16  = lane & 15;
    const int r    = bid >> 3;        // row-group
    const int c    = bid & 7;         // shard
    const int rowbase = r * RG;
    const int jbase   = c * JC;
    const int myrow   = wave * 16 + l16;

    // double-buffered by step parity: compute(t) reads [t&1]; producer
    // self-writes h_{t+1} into [(t+1)&1]; gather(t) fills [t&1] pre-B1.
    __shared__ __align__(16) f16 hg[2][RG][HH + 8];
    __shared__ __align__(16) f16 xsh[2][RG][II + 8];

    // ---- one-time: weight shards -> constant register B-fragments ----
    // B-frag: lane holds BT[n=lane&15][k=quad*8+j], j=0..7 (verified R0)
    f16x8 bf[16];   // W_hh shard, K=512 -> 16 k-steps
    f16x8 xbf[4];   // W_xh shard, K=128 -> 4 k-steps
    f16x8 bfo[2];   // W_out, this block's K-range [c*64, c*64+64)
    {
        const float* wp = Whh + (size_t)(jbase + myrow) * HH + quad * 8;
        #pragma unroll
        for (int ks = 0; ks < 16; ++ks) {
            float4 u = *(const float4*)(wp + ks * 32);
            float4 v = *(const float4*)(wp + ks * 32 + 4);
            f16x8 tv;
            tv[0]=(f16)u.x; tv[1]=(f16)u.y; tv[2]=(f16)u.z; tv[3]=(f16)u.w;
            tv[4]=(f16)v.x; tv[5]=(f16)v.y; tv[6]=(f16)v.z; tv[7]=(f16)v.w;
            bf[ks] = tv;
        }
        const float* wq = Wxh + (size_t)(jbase + myrow) * II + quad * 8;
        #pragma unroll
        for (int ks = 0; ks < 4; ++ks) {
            float4 u = *(const float4*)(wq + ks * 32);
            float4 v = *(const float4*)(wq + ks * 32 + 4);
            f16x8 tv;
            tv[0]=(f16)u.x; tv[1]=(f16)u.y; tv[2]=(f16)u.z; tv[3]=(f16)u.w;
            tv[4]=(f16)v.x; tv[5]=(f16)v.y; tv[6]=(f16)v.z; tv[7]=(f16)v.w;
            xbf[ks] = tv;
        }
        const float* wo = Wout + (size_t)myrow * HH + c * 64 + quad * 8;
        #pragma unroll
        for (int ks = 0; ks < 2; ++ks) {
            float4 u = *(const float4*)(wo + ks * 32);
            float4 v = *(const float4*)(wo + ks * 32 + 4);
            f16x8 tv;
            tv[0]=(f16)u.x; tv[1]=(f16)u.y; tv[2]=(f16)u.z; tv[3]=(f16)u.w;
            tv[4]=(f16)v.x; tv[5]=(f16)v.y; tv[6]=(f16)v.z; tv[7]=(f16)v.w;
            bfo[ks] = tv;
        }
    }
    const float biash = bh[jbase + myrow];
    const float biaso = (c == 0) ? bout[myrow] : 0.0f;

    // zero hg (t=0 uses h_0 = 0; buffer 1 is fully written before first read)
    for (int p = tid; p < RG * (HH + 8); p += 256)   // u32 count = 2*16*520/2
        ((unsigned int*)hg)[p] = 0u;

    // fp32 integrator state: lane owns h[m=quad*4+reg][jbase+myrow]
    float hreg[4] = {0.f, 0.f, 0.f, 0.f};

    // gather geometry: thread j8 owns u64-column j8 (col pair 2*j8, 2*j8+1)
    // across all 16 rows; the whole column comes from ONE producer shard.
    const int j8     = tid;          // 0..255
    const int gshard = j8 >> 5;      // (2*j8)/64

    // x prefetch for t=0: 2 float4/thread cover 16 rows x 128 cols
    float4 xpf0, xpf1;
    {
        int p0 = tid, p1 = tid + 256;
        xpf0 = ((const float4*)(x + ((size_t)(rowbase + (p0 >> 5)) * TT + 0) * II))[p0 & 31];
        xpf1 = ((const float4*)(x + ((size_t)(rowbase + (p1 >> 5)) * TT + 0) * II))[p1 & 31];
    }

    __syncthreads();

    for (int t = 0; t <= TT; ++t) {
        const int pcur = t & 1;

        // ---- stage x_t from prefetch regs into xsh[pcur] ----
        if (t < TT) {
            int p0 = tid, p1 = tid + 256;
            f16* d0 = &xsh[pcur][p0 >> 5][(p0 & 31) * 4];
            d0[0]=(f16)xpf0.x; d0[1]=(f16)xpf0.y; d0[2]=(f16)xpf0.z; d0[3]=(f16)xpf0.w;
            f16* d1 = &xsh[pcur][p1 >> 5][(p1 & 31) * 4];
            d1[0]=(f16)xpf1.x; d1[1]=(f16)xpf1.y; d1[2]=(f16)xpf1.z; d1[3]=(f16)xpf1.w;
        }
        // ---- issue x_{t+1} prefetch; poll's vmcnt waits absorb it ----
        if (t + 1 < TT) {
            int p0 = tid, p1 = tid + 256;
            xpf0 = ((const float4*)(x + ((size_t)(rowbase + (p0 >> 5)) * TT + (t + 1)) * II))[p0 & 31];
            xpf1 = ((const float4*)(x + ((size_t)(rowbase + (p1 >> 5)) * TT + (t + 1)) * II))[p1 & 31];
        }
        // ---- single-hop gather: poll tagged u64s, payload rides with tag ----
        if (t >= 1 && gshard != c) {
            const unsigned long long* src = hbuf
                + (size_t)pcur * (BB * HH / 2)
                + (size_t)rowbase * (HH / 2) + j8;
            const unsigned int tg = (unsigned)t;
            unsigned long long v[16];
            #pragma unroll
            for (int i = 0; i < 16; ++i)
                v[i] = __hip_atomic_load(src + (size_t)i * (HH / 2),
                                         __ATOMIC_RELAXED, __HIP_MEMORY_SCOPE_AGENT);
            for (;;) {
                bool any = false;
                #pragma unroll
                for (int i = 0; i < 16; ++i)
                    any |= ((unsigned)(v[i] >> 32) != tg);
                if (!any) break;
                #pragma unroll
                for (int i = 0; i < 16; ++i)
                    if ((unsigned)(v[i] >> 32) != tg)
                        v[i] = __hip_atomic_load(src + (size_t)i * (HH / 2),
                                                 __ATOMIC_RELAXED, __HIP_MEMORY_SCOPE_AGENT);
            }
            #pragma unroll
            for (int i = 0; i < 16; ++i)
                *(unsigned int*)&hg[pcur][i][j8 * 2] = (unsigned int)v[i];
        }
        __syncthreads();   // B1: hg[pcur] + xsh[pcur] ready (only barrier/step)

        if (t < TT) {
            // pre = h_t.W_hh^T + x_t.W_xh^T + b_h
            f32x4 acc0 = {0.f,0.f,0.f,0.f}, acc1 = {0.f,0.f,0.f,0.f};
            #pragma unroll
            for (int ks = 0; ks < 16; ks += 2) {
                f16x8 a0 = *(const f16x8*)&hg[pcur][l16][ks * 32 + quad * 8];
                f16x8 a1 = *(const f16x8*)&hg[pcur][l16][(ks + 1) * 32 + quad * 8];
                acc0 = __builtin_amdgcn_mfma_f32_16x16x32_f16(a0, bf[ks], acc0, 0, 0, 0);
                acc1 = __builtin_amdgcn_mfma_f32_16x16x32_f16(a1, bf[ks + 1], acc1, 0, 0, 0);
            }
            #pragma unroll
            for (int ks = 0; ks < 4; ks += 2) {
                f16x8 a0 = *(const f16x8*)&xsh[pcur][l16][ks * 32 + quad * 8];
                f16x8 a1 = *(const f16x8*)&xsh[pcur][l16][(ks + 1) * 32 + quad * 8];
                acc0 = __builtin_amdgcn_mfma_f32_16x16x32_f16(a0, xbf[ks], acc0, 0, 0, 0);
                acc1 = __builtin_amdgcn_mfma_f32_16x16x32_f16(a1, xbf[ks + 1], acc1, 0, 0, 0);
            }
            // phi + leaky update; pack lane-pairs; fire-and-forget tagged u64
            unsigned long long* dst64 = hbuf + (size_t)((t + 1) & 1) * (BB * HH / 2);
            const unsigned long long tagw = ((unsigned long long)(unsigned)(t + 1)) << 32;
            unsigned int hb[4];
            #pragma unroll
            for (int reg = 0; reg < 4; ++reg) {
                float pre = acc0[reg] + acc1[reg] + biash;
                float z = 8.f * pre;
                float ph = (z > 20.f) ? pre : (__logf(1.f + __expf(z)) * 0.125f);
                float hn = 0.8f * hreg[reg] + 0.2f * ph;
                hreg[reg] = hn;
                hb[reg] = (unsigned int)__builtin_bit_cast(unsigned short, (f16)hn);
            }
            #pragma unroll
            for (int reg = 0; reg < 4; ++reg) {
                unsigned int ob = (unsigned int)__shfl_xor((int)hb[reg], 1, 64);
                if ((lane & 1) == 0) {
                    unsigned int pair = hb[reg] | (ob << 16);
                    size_t eidx = (size_t)(rowbase + quad * 4 + reg) * HH + jbase + myrow;
                    // tag+payload in ONE atomic u64: no drain, no flag
                    __hip_atomic_store(dst64 + (eidx >> 1), tagw | (unsigned long long)pair,
                                       __ATOMIC_RELAXED, __HIP_MEMORY_SCOPE_AGENT);
                    // own-shard short-circuit into next-parity LDS buffer
                    *(unsigned int*)&hg[(t + 1) & 1][quad * 4 + reg][jbase + myrow] = pair;
                }
            }
        }

        // ---- readout partial: y_{t-1} += h_t[:, c*64:c*64+64] . W_out^T ----
        if (t >= 1) {
            f32x4 ya = {0.f,0.f,0.f,0.f};
            f16x8 a0 = *(const f16x8*)&hg[pcur][l16][c * 64 + quad * 8];
            f16x8 a1 = *(const f16x8*)&hg[pcur][l16][c * 64 + 32 + quad * 8];
            ya = __builtin_amdgcn_mfma_f32_16x16x32_f16(a0, bfo[0], ya, 0, 0, 0);
            ya = __builtin_amdgcn_mfma_f32_16x16x32_f16(a1, bfo[1], ya, 0, 0, 0);
            #pragma unroll
            for (int reg = 0; reg < 4; ++reg)
                atomicAdd(yout + ((size_t)(rowbase + quad * 4 + reg) * TT + (t - 1)) * OO + myrow,
                          ya[reg] + biaso);
        }
        // no B2: parity double-buffering makes next iter's B1 the only fence
    }
}

extern "C" void kernel_launch(void* const* d_in, const int* in_sizes, int n_in,
                              void* d_out, int out_size, void* d_ws, size_t ws_size,
                              hipStream_t stream)
{
    const float* x    = (const float*)d_in[0];
    const float* Wxh  = (const float*)d_in[1];
    const float* Whh  = (const float*)d_in[2];
    const float* bh   = (const float*)d_in[3];
    const float* Wout = (const float*)d_in[4];
    const float* bout = (const float*)d_in[5];
    float* yout = (float*)d_out;

    unsigned long long* hbuf = (unsigned long long*)d_ws;
    const size_t hbuf_bytes = (size_t)2 * BB * (HH / 2) * sizeof(unsigned long long); // 1 MB

    if (ws_size < hbuf_bytes) return;

    hipMemsetAsync(hbuf, 0, hbuf_bytes, stream);          // tags start at 0; expected tags 1..512
    hipMemsetAsync(yout, 0, (size_t)out_size * sizeof(float), stream); // atomic targets

    // 128 blocks (<=256 CUs, ~42KB LDS, ~150 VGPR) -> all co-resident.
    eirnn_persist<<<dim3(NG * NC), dim3(256), 0, stream>>>(
        x, Wxh, Whh, bh, Wout, bout, yout, hbuf);
}